// Round 15
// baseline (183.740 us; speedup 1.0000x reference)
//
#include <hip/hip_runtime.h>
#include <hip/hip_bf16.h>
#include <math.h>

#define GLOBAL_AS __attribute__((address_space(1)))
#define LDS_AS __attribute__((address_space(3)))

typedef __bf16 bf16x8 __attribute__((ext_vector_type(8)));
typedef __bf16 bf16x4 __attribute__((ext_vector_type(4)));
typedef float f32x4 __attribute__((ext_vector_type(4)));
typedef float f32x16 __attribute__((ext_vector_type(16)));
typedef unsigned short u16x8 __attribute__((ext_vector_type(8)));

static constexpr int BB = 4, SS = 2048, DD = 1024, HH = 16, DKK = 64;
static constexpr int MM = BB * SS;      // 8192 rows
static constexpr int NQKV = 3 * DD;     // 3072
static constexpr int NQT = SS / 128;    // 16 q-tiles

__device__ inline unsigned int cvt_pk_bf16(float lo, float hi) {
  unsigned int r;
  asm("v_cvt_pk_bf16_f32 %0, %1, %2" : "=v"(r) : "v"(lo), "v"(hi));
  return r;
}

// ---------------- merged fp32 -> bf16 convert: [x | w_q | w_k | w_v | w_o] -> ws ----------------
__global__ __launch_bounds__(256) void cvt_all(const float* __restrict__ x,
                                               const float* __restrict__ w_q,
                                               const float* __restrict__ w_k,
                                               const float* __restrict__ w_v,
                                               const float* __restrict__ w_o,
                                               __bf16* __restrict__ ws) {
  const int idx = blockIdx.x * blockDim.x + threadIdx.x;   // float4 index
  constexpr int XN4 = MM * DD / 4;          // 2097152
  constexpr int WN4 = DD * DD / 4;          // 262144
  const float* src;
  int off;
  if (idx < XN4) { src = x; off = idx; }
  else {
    int j = idx - XN4;
    int sel = j >> 18;                      // WN4 = 2^18
    off = j & (WN4 - 1);
    src = (sel == 0) ? w_q : (sel == 1) ? w_k : (sel == 2) ? w_v : w_o;
  }
  float4 v = reinterpret_cast<const float4*>(src)[off];
  bf16x4 o;
  o[0] = (__bf16)v.x; o[1] = (__bf16)v.y; o[2] = (__bf16)v.z; o[3] = (__bf16)v.w;
  *reinterpret_cast<bf16x4*>(ws + (size_t)idx * 4) = o;
}

// ================= m97-style 128x128 NT GEMM, 3 blocks/CU =================
// (R10-proven: bank conflicts = 0)
template <int MODE>
__global__ __launch_bounds__(256, 3) void gemm128(const unsigned short* __restrict__ A,
                                                  const unsigned short* __restrict__ Bm,
                                                  void* __restrict__ Cout,
                                                  const float* __restrict__ bias,
                                                  unsigned short* __restrict__ vt,
                                                  int Ndim, int K) {
  __shared__ __align__(16) unsigned short SA[128 * 64];
  __shared__ __align__(16) unsigned short SB[128 * 64];
  const int tid = threadIdx.x, wv = tid >> 6, ln = tid & 63;
  const int wm = wv >> 1, wn = wv & 1;
  const int cl = ln & 15, ck = ln >> 4;

  const int gx = gridDim.x, nwg = gx * gridDim.y;
  const int qch = nwg >> 3;
  int lid = blockIdx.y * gx + blockIdx.x;
  lid = (lid & 7) * qch + (lid >> 3);
  const int bn0 = (lid % gx) * 128;
  const int bm0 = (lid / gx) * 128;

  const int KT = K >> 6;
  const int sr = tid >> 3;
  int chk[2];
  chk[0] = ((ck ^ (cl & 7)) << 3);
  chk[1] = (((4 + ck) ^ (cl & 7)) << 3);

  f32x4 acc[4][4] = {};

  for (int kt = 0; kt < KT; ++kt) {
    const int k0 = kt * 64;
#pragma unroll
    for (int i = 0; i < 4; ++i) {
      const int row = i * 32 + sr;
      const int sc = (((tid & 7) ^ (row & 7)) << 3);
      const unsigned short* ga = A + (size_t)(bm0 + row) * K + k0 + sc;
      __builtin_amdgcn_global_load_lds((GLOBAL_AS void*)ga,
          (LDS_AS void*)(SA + i * 2048 + tid * 8), 16, 0, 0);
      const unsigned short* gb = Bm + (size_t)(bn0 + row) * K + k0 + sc;
      __builtin_amdgcn_global_load_lds((GLOBAL_AS void*)gb,
          (LDS_AS void*)(SB + i * 2048 + tid * 8), 16, 0, 0);
    }
    __syncthreads();

    bf16x8 af[4][2], bf[4][2];
#pragma unroll
    for (int mf = 0; mf < 4; ++mf) {
      const int row = wm * 64 + mf * 16 + cl;
#pragma unroll
      for (int kk = 0; kk < 2; ++kk)
        af[mf][kk] = *reinterpret_cast<const bf16x8*>(SA + row * 64 + chk[kk]);
    }
#pragma unroll
    for (int nf = 0; nf < 4; ++nf) {
      const int row = wn * 64 + nf * 16 + cl;
#pragma unroll
      for (int kk = 0; kk < 2; ++kk)
        bf[nf][kk] = *reinterpret_cast<const bf16x8*>(SB + row * 64 + chk[kk]);
    }
    __builtin_amdgcn_s_setprio(1);
#pragma unroll
    for (int mf = 0; mf < 4; ++mf)
#pragma unroll
      for (int nf = 0; nf < 4; ++nf)
#pragma unroll
        for (int kk = 0; kk < 2; ++kk)
          acc[mf][nf] = __builtin_amdgcn_mfma_f32_16x16x32_bf16(af[mf][kk], bf[nf][kk], acc[mf][nf], 0, 0, 0);
    __builtin_amdgcn_s_setprio(0);
    __syncthreads();
  }

#pragma unroll
  for (int mf = 0; mf < 4; ++mf) {
#pragma unroll
    for (int nf = 0; nf < 4; ++nf) {
      const int col = bn0 + wn * 64 + nf * 16 + cl;
      const int row0 = bm0 + wm * 64 + mf * 16 + ck * 4;
      if constexpr (MODE == 2) {
        if (col >= 2 * DD) {   // V part -> vt[b,h,dk,s], packed 8B
          const int hcol = col - 2 * DD;
          const int hh = hcol >> 6, dk = hcol & 63;
          const int bb_ = row0 >> 11, s0 = row0 & 2047;
          bf16x4 pv;
#pragma unroll
          for (int r = 0; r < 4; ++r) pv[r] = (__bf16)acc[mf][nf][r];
          *reinterpret_cast<bf16x4*>(vt + ((size_t)((bb_ * HH + hh) * 64 + dk)) * SS + s0) = pv;
          continue;
        }
      }
#pragma unroll
      for (int r = 0; r < 4; ++r) {
        float v = acc[mf][nf][r];
        if constexpr (MODE == 0) {
          ((float*)Cout)[(size_t)(row0 + r) * Ndim + col] = v + bias[col];
        } else {
          if (col < DD) v *= 0.18033688011112042f;  // 0.125*log2(e)
          ((__bf16*)Cout)[(size_t)(row0 + r) * Ndim + col] = (__bf16)v;
        }
      }
    }
  }
}

// ---------------- causal flash attention (fused heavy+light 8-wave blocks) ----------------
// grid (NQT/2, H, B), 512 threads. Waves 0-3 compute q-tile (NQT-1-pi), waves 4-7 q-tile pi,
// SHARING one staged KV stream (light range is a prefix of heavy range). Swapped-operand
// 32x32 MFMA, in-register P (cvt_pk + permlane32_swap), ones-MFMA row-sums, defer-rescale,
// quad-conflict-free LDS swizzle s(row) = (row&7)^((row>>3)&3).
__global__ __launch_bounds__(512) void attn_kernel(const unsigned short* __restrict__ qkv,
                                                   const unsigned short* __restrict__ vt,
                                                   unsigned short* __restrict__ attn_out) {
  const int pi = blockIdx.x, h = blockIdx.y, b = blockIdx.z;
  const int tid = threadIdx.x, wv = tid >> 6, ln = tid & 63;
  const int l31 = ln & 31, hi = ln >> 5;
  const int bh = b * HH + h;
  const int sxr = (l31 & 7) ^ ((l31 >> 3) & 3);   // read-side row swizzle (row = cc*32+l31)
  const int wq = wv & 3;                          // slot within the tile (32-row band)
  const int qt = (wv < 4) ? (NQT - 1 - pi) : pi;  // heavy group / light group

  __shared__ __align__(16) unsigned short Ks[2][64 * 64];
  __shared__ __align__(16) unsigned short Vs[2][64 * 64];

  bf16x8 vones;
#pragma unroll
  for (int j = 0; j < 8; ++j) vones[j] = (__bf16)1.0f;

  auto stage = [&](int bsel, int kv0s) {   // 8 waves: 1 K-load + 1 V-load each
    const int row = wv * 8 + (ln >> 3);
    const int sch = (ln & 7) ^ (row & 7) ^ ((row >> 3) & 3);   // pre-swizzled source chunk
    const unsigned short* gk = qkv + ((size_t)(b * SS + kv0s + row) * NQKV + DD + h * DKK + sch * 8);
    __builtin_amdgcn_global_load_lds((GLOBAL_AS void*)gk, (LDS_AS void*)(&Ks[bsel][wv * 512]), 16, 0, 0);
    const unsigned short* gv = vt + ((size_t)(bh * 64 + row) * SS + kv0s + sch * 8);
    __builtin_amdgcn_global_load_lds((GLOBAL_AS void*)gv, (LDS_AS void*)(&Vs[bsel][wv * 512]), 16, 0, 0);
  };

  const int q0w = qt * 128 + wq * 32;
  const int qq = q0w + l31;

  bf16x8 qf[4];
#pragma unroll
  for (int kkk = 0; kkk < 4; ++kkk)
    qf[kkk] = *reinterpret_cast<const bf16x8*>(
        qkv + (size_t)(b * SS + qq) * NQKV + h * DKK + kkk * 16 + hi * 8);

  f32x16 ot[2] = {};
  f32x16 lsum = {};
  float mrow = -INFINITY;

  const int nt = 2 * (NQT - 1 - pi) + 2;   // heavy range; light's is a prefix
  stage(0, 0);
  __syncthreads();
  int buf = 0;

  for (int t = 0; t < nt; ++t) {
    const int kv0 = t * 64;
    if (t + 1 < nt) stage(buf ^ 1, (t + 1) * 64);

    if (kv0 <= q0w + 31) {   // wave-uniform causal skip (light waves idle past their range)
      const unsigned short* kb = &Ks[buf][0];
      const unsigned short* vb = &Vs[buf][0];

      f32x16 st[2];
      __builtin_amdgcn_s_setprio(1);
#pragma unroll
      for (int cc = 0; cc < 2; ++cc) {
        f32x16 z = {};
#pragma unroll
        for (int kkk = 0; kkk < 4; ++kkk) {
          bf16x8 kf = *reinterpret_cast<const bf16x8*>(
              kb + (cc * 32 + l31) * 64 + (((kkk * 2 + hi) ^ sxr) * 8));
          z = __builtin_amdgcn_mfma_f32_32x32x16_bf16(kf, qf[kkk], z, 0, 0, 0);
        }
        st[cc] = z;
      }
      __builtin_amdgcn_s_setprio(0);

      if (kv0 + 63 > q0w) {
        const int kvb = kv0 + 4 * hi;
#pragma unroll
        for (int cc = 0; cc < 2; ++cc)
#pragma unroll
          for (int r = 0; r < 16; ++r) {
            const int kv = kvb + cc * 32 + (r & 3) + 8 * (r >> 2);
            st[cc][r] = (kv <= qq) ? st[cc][r] : -INFINITY;
          }
      }

      float tm = st[0][0];
#pragma unroll
      for (int r = 1; r < 16; ++r) tm = fmaxf(tm, st[0][r]);
#pragma unroll
      for (int r = 0; r < 16; ++r) tm = fmaxf(tm, st[1][r]);
      tm = fmaxf(tm, __shfl_xor(tm, 32));

      if (__any(tm - mrow > 8.0f)) {
        float mn = fmaxf(mrow, tm);
        float al = __builtin_amdgcn_exp2f(mrow - mn);
        mrow = mn;
        lsum *= al;
        ot[0] *= al;
        ot[1] *= al;
      }

#pragma unroll
      for (int cc = 0; cc < 2; ++cc)
#pragma unroll
        for (int r = 0; r < 16; ++r)
          st[cc][r] = __builtin_amdgcn_exp2f(st[cc][r] - mrow);

      unsigned int pk[2][4], pk2[2][4];
#pragma unroll
      for (int cc = 0; cc < 2; ++cc)
#pragma unroll
        for (int g = 0; g < 4; ++g) {
          pk[cc][g]  = cvt_pk_bf16(st[cc][4 * g + 0], st[cc][4 * g + 1]);
          pk2[cc][g] = cvt_pk_bf16(st[cc][4 * g + 2], st[cc][4 * g + 3]);
        }

      __builtin_amdgcn_s_setprio(1);
#pragma unroll
      for (int ks = 0; ks < 4; ++ks) {
        const int cc = ks >> 1, g0 = 2 * (ks & 1), g1 = g0 + 1;
        unsigned int Aw = pk[cc][g0], Bw = pk[cc][g1];
        asm volatile("v_permlane32_swap_b32 %0, %1" : "+v"(Aw), "+v"(Bw));
        unsigned int A2 = pk2[cc][g0], B2 = pk2[cc][g1];
        asm volatile("v_permlane32_swap_b32 %0, %1" : "+v"(A2), "+v"(B2));
        union { unsigned int u[4]; bf16x8 v; } pb;
        pb.u[0] = Aw; pb.u[1] = A2; pb.u[2] = Bw; pb.u[3] = B2;
        lsum = __builtin_amdgcn_mfma_f32_32x32x16_bf16(vones, pb.v, lsum, 0, 0, 0);
#pragma unroll
        for (int dc = 0; dc < 2; ++dc) {
          bf16x8 vf = *reinterpret_cast<const bf16x8*>(
              vb + (dc * 32 + l31) * 64 + (((ks * 2 + hi) ^ sxr) * 8));
          ot[dc] = __builtin_amdgcn_mfma_f32_32x32x16_bf16(vf, pb.v, ot[dc], 0, 0, 0);
        }
      }
      __builtin_amdgcn_s_setprio(0);
    }

    __syncthreads();
    buf ^= 1;
  }

  const float inv = 1.0f / lsum[0];
  __bf16* aout = (__bf16*)attn_out + (size_t)(b * SS + qq) * DD + h * DKK;
#pragma unroll
  for (int dc = 0; dc < 2; ++dc)
#pragma unroll
    for (int g = 0; g < 4; ++g) {
      uint2 pw;
      pw.x = cvt_pk_bf16(ot[dc][4 * g + 0] * inv, ot[dc][4 * g + 1] * inv);
      pw.y = cvt_pk_bf16(ot[dc][4 * g + 2] * inv, ot[dc][4 * g + 3] * inv);
      *reinterpret_cast<uint2*>(aout + dc * 32 + 4 * hi + 8 * g) = pw;
    }
}

// ---------------- launch ----------------
extern "C" void kernel_launch(void* const* d_in, const int* in_sizes, int n_in,
                              void* d_out, int out_size, void* d_ws, size_t ws_size,
                              hipStream_t stream) {
  const float* x = (const float*)d_in[0];
  const float* w_q = (const float*)d_in[1];
  const float* w_k = (const float*)d_in[2];
  const float* w_v = (const float*)d_in[3];
  const float* w_o = (const float*)d_in[4];
  const float* b_o = (const float*)d_in[5];
  float* out = (float*)d_out;

  unsigned short* ws = (unsigned short*)d_ws;
  unsigned short* x_bf = ws;                               // 8192*1024
  unsigned short* w_qkv = x_bf + (size_t)MM * DD;          // 3072*1024
  unsigned short* w_obf = w_qkv + (size_t)NQKV * DD;       // 1024*1024
  unsigned short* qkv = w_obf + (size_t)DD * DD;           // 8192*3072 (V region unused)
  unsigned short* vt = qkv + (size_t)MM * NQKV;            // B*H*DK*S = 8388608
  unsigned short* attn = vt + (size_t)BB * HH * DKK * SS;  // 8192*1024

  // merged converts: [x | w_q | w_k | w_v | w_o] -> contiguous bf16 ws region
  constexpr int TOTAL4 = (MM * DD + 4 * DD * DD) / 4;      // 3145728 float4s
  cvt_all<<<TOTAL4 / 256, 256, 0, stream>>>(x, w_q, w_k, w_v, w_o, (__bf16*)ws);

  // QKV projection (m97-style 128^2, 3 blocks/CU; Q prescaled; V -> vt transposed)
  gemm128<2><<<dim3(NQKV / 128, MM / 128), 256, 0, stream>>>(x_bf, w_qkv, qkv, nullptr, vt, NQKV, DD);

  // attention (fused heavy+light pair, 8 waves/block sharing one KV stream)
  attn_kernel<<<dim3(NQT / 2, HH, BB), 512, 0, stream>>>(qkv, vt, attn);

  // output projection: [8192,1024] = attn @ w_o^T + b_o
  gemm128<0><<<dim3(DD / 128, MM / 128), 256, 0, stream>>>(attn, w_obf, out, b_o, nullptr, DD, DD);
}

// Round 16
// 154.441 us; speedup vs baseline: 1.1897x; 1.1897x over previous
//
#include <hip/hip_runtime.h>
#include <hip/hip_bf16.h>
#include <math.h>

#define GLOBAL_AS __attribute__((address_space(1)))
#define LDS_AS __attribute__((address_space(3)))

typedef __bf16 bf16x8 __attribute__((ext_vector_type(8)));
typedef __bf16 bf16x4 __attribute__((ext_vector_type(4)));
typedef float f32x4 __attribute__((ext_vector_type(4)));
typedef float f32x16 __attribute__((ext_vector_type(16)));
typedef unsigned short u16x8 __attribute__((ext_vector_type(8)));

static constexpr int BB = 4, SS = 2048, DD = 1024, HH = 16, DKK = 64;
static constexpr int MM = BB * SS;      // 8192 rows
static constexpr int NQKV = 3 * DD;     // 3072
static constexpr int NQT = SS / 128;    // 16 q-tiles

__device__ inline unsigned int cvt_pk_bf16(float lo, float hi) {
  unsigned int r;
  asm("v_cvt_pk_bf16_f32 %0, %1, %2" : "=v"(r) : "v"(lo), "v"(hi));
  return r;
}

// ---------------- merged fp32 -> bf16 convert: [x | w_q | w_k | w_v | w_o] -> ws ----------------
__global__ __launch_bounds__(256) void cvt_all(const float* __restrict__ x,
                                               const float* __restrict__ w_q,
                                               const float* __restrict__ w_k,
                                               const float* __restrict__ w_v,
                                               const float* __restrict__ w_o,
                                               __bf16* __restrict__ ws) {
  const int idx = blockIdx.x * blockDim.x + threadIdx.x;   // float4 index
  constexpr int XN4 = MM * DD / 4;          // 2097152
  constexpr int WN4 = DD * DD / 4;          // 262144
  const float* src;
  int off;
  if (idx < XN4) { src = x; off = idx; }
  else {
    int j = idx - XN4;
    int sel = j >> 18;                      // WN4 = 2^18
    off = j & (WN4 - 1);
    src = (sel == 0) ? w_q : (sel == 1) ? w_k : (sel == 2) ? w_v : w_o;
  }
  float4 v = reinterpret_cast<const float4*>(src)[off];
  bf16x4 o;
  o[0] = (__bf16)v.x; o[1] = (__bf16)v.y; o[2] = (__bf16)v.z; o[3] = (__bf16)v.w;
  *reinterpret_cast<bf16x4*>(ws + (size_t)idx * 4) = o;
}

// ================= m97-style 128x128 NT GEMM, 3 blocks/CU =================
// (R10-proven: bank conflicts = 0)
template <int MODE>
__global__ __launch_bounds__(256, 3) void gemm128(const unsigned short* __restrict__ A,
                                                  const unsigned short* __restrict__ Bm,
                                                  void* __restrict__ Cout,
                                                  const float* __restrict__ bias,
                                                  unsigned short* __restrict__ vt,
                                                  int Ndim, int K) {
  __shared__ __align__(16) unsigned short SA[128 * 64];
  __shared__ __align__(16) unsigned short SB[128 * 64];
  const int tid = threadIdx.x, wv = tid >> 6, ln = tid & 63;
  const int wm = wv >> 1, wn = wv & 1;
  const int cl = ln & 15, ck = ln >> 4;

  const int gx = gridDim.x, nwg = gx * gridDim.y;
  const int qch = nwg >> 3;
  int lid = blockIdx.y * gx + blockIdx.x;
  lid = (lid & 7) * qch + (lid >> 3);
  const int bn0 = (lid % gx) * 128;
  const int bm0 = (lid / gx) * 128;

  const int KT = K >> 6;
  const int sr = tid >> 3;
  int chk[2];
  chk[0] = ((ck ^ (cl & 7)) << 3);
  chk[1] = (((4 + ck) ^ (cl & 7)) << 3);

  f32x4 acc[4][4] = {};

  for (int kt = 0; kt < KT; ++kt) {
    const int k0 = kt * 64;
#pragma unroll
    for (int i = 0; i < 4; ++i) {
      const int row = i * 32 + sr;
      const int sc = (((tid & 7) ^ (row & 7)) << 3);
      const unsigned short* ga = A + (size_t)(bm0 + row) * K + k0 + sc;
      __builtin_amdgcn_global_load_lds((GLOBAL_AS void*)ga,
          (LDS_AS void*)(SA + i * 2048 + tid * 8), 16, 0, 0);
      const unsigned short* gb = Bm + (size_t)(bn0 + row) * K + k0 + sc;
      __builtin_amdgcn_global_load_lds((GLOBAL_AS void*)gb,
          (LDS_AS void*)(SB + i * 2048 + tid * 8), 16, 0, 0);
    }
    __syncthreads();

    bf16x8 af[4][2], bf[4][2];
#pragma unroll
    for (int mf = 0; mf < 4; ++mf) {
      const int row = wm * 64 + mf * 16 + cl;
#pragma unroll
      for (int kk = 0; kk < 2; ++kk)
        af[mf][kk] = *reinterpret_cast<const bf16x8*>(SA + row * 64 + chk[kk]);
    }
#pragma unroll
    for (int nf = 0; nf < 4; ++nf) {
      const int row = wn * 64 + nf * 16 + cl;
#pragma unroll
      for (int kk = 0; kk < 2; ++kk)
        bf[nf][kk] = *reinterpret_cast<const bf16x8*>(SB + row * 64 + chk[kk]);
    }
    __builtin_amdgcn_s_setprio(1);
#pragma unroll
    for (int mf = 0; mf < 4; ++mf)
#pragma unroll
      for (int nf = 0; nf < 4; ++nf)
#pragma unroll
        for (int kk = 0; kk < 2; ++kk)
          acc[mf][nf] = __builtin_amdgcn_mfma_f32_16x16x32_bf16(af[mf][kk], bf[nf][kk], acc[mf][nf], 0, 0, 0);
    __builtin_amdgcn_s_setprio(0);
    __syncthreads();
  }

#pragma unroll
  for (int mf = 0; mf < 4; ++mf) {
#pragma unroll
    for (int nf = 0; nf < 4; ++nf) {
      const int col = bn0 + wn * 64 + nf * 16 + cl;
      const int row0 = bm0 + wm * 64 + mf * 16 + ck * 4;
      if constexpr (MODE == 2) {
        if (col >= 2 * DD) {   // V part -> vt[b,h,dk,s], packed 8B
          const int hcol = col - 2 * DD;
          const int hh = hcol >> 6, dk = hcol & 63;
          const int bb_ = row0 >> 11, s0 = row0 & 2047;
          bf16x4 pv;
#pragma unroll
          for (int r = 0; r < 4; ++r) pv[r] = (__bf16)acc[mf][nf][r];
          *reinterpret_cast<bf16x4*>(vt + ((size_t)((bb_ * HH + hh) * 64 + dk)) * SS + s0) = pv;
          continue;
        }
      }
#pragma unroll
      for (int r = 0; r < 4; ++r) {
        float v = acc[mf][nf][r];
        if constexpr (MODE == 0) {
          ((float*)Cout)[(size_t)(row0 + r) * Ndim + col] = v + bias[col];
        } else {
          if (col < DD) v *= 0.18033688011112042f;  // 0.125*log2(e)
          ((__bf16*)Cout)[(size_t)(row0 + r) * Ndim + col] = (__bf16)v;
        }
      }
    }
  }
}

// ---------------- causal flash attention (fused heavy+light 8-wave blocks) ----------------
// grid (NQT/2, H, B), 512 threads, __launch_bounds__(512,4): VGPR cap 128 >= natural ~116,
// 2 blocks/CU = 16 waves/CU. Waves 0-3 compute q-tile (NQT-1-pi), waves 4-7 q-tile pi,
// SHARING one staged KV stream (light range is a prefix of heavy range).
__global__ __launch_bounds__(512, 4) void attn_kernel(const unsigned short* __restrict__ qkv,
                                                      const unsigned short* __restrict__ vt,
                                                      unsigned short* __restrict__ attn_out) {
  const int pi = blockIdx.x, h = blockIdx.y, b = blockIdx.z;
  const int tid = threadIdx.x, wv = tid >> 6, ln = tid & 63;
  const int l31 = ln & 31, hi = ln >> 5;
  const int bh = b * HH + h;
  const int sxr = (l31 & 7) ^ ((l31 >> 3) & 3);   // read-side row swizzle (row = cc*32+l31)
  const int wq = wv & 3;                          // slot within the tile (32-row band)
  const int qt = (wv < 4) ? (NQT - 1 - pi) : pi;  // heavy group / light group

  __shared__ __align__(16) unsigned short Ks[2][64 * 64];
  __shared__ __align__(16) unsigned short Vs[2][64 * 64];

  bf16x8 vones;
#pragma unroll
  for (int j = 0; j < 8; ++j) vones[j] = (__bf16)1.0f;

  auto stage = [&](int bsel, int kv0s) {   // 8 waves: 1 K-load + 1 V-load each
    const int row = wv * 8 + (ln >> 3);
    const int sch = (ln & 7) ^ (row & 7) ^ ((row >> 3) & 3);   // pre-swizzled source chunk
    const unsigned short* gk = qkv + ((size_t)(b * SS + kv0s + row) * NQKV + DD + h * DKK + sch * 8);
    __builtin_amdgcn_global_load_lds((GLOBAL_AS void*)gk, (LDS_AS void*)(&Ks[bsel][wv * 512]), 16, 0, 0);
    const unsigned short* gv = vt + ((size_t)(bh * 64 + row) * SS + kv0s + sch * 8);
    __builtin_amdgcn_global_load_lds((GLOBAL_AS void*)gv, (LDS_AS void*)(&Vs[bsel][wv * 512]), 16, 0, 0);
  };

  const int q0w = qt * 128 + wq * 32;
  const int qq = q0w + l31;

  bf16x8 qf[4];
#pragma unroll
  for (int kkk = 0; kkk < 4; ++kkk)
    qf[kkk] = *reinterpret_cast<const bf16x8*>(
        qkv + (size_t)(b * SS + qq) * NQKV + h * DKK + kkk * 16 + hi * 8);

  f32x16 ot[2] = {};
  f32x16 lsum = {};
  float mrow = -INFINITY;

  const int nt = 2 * (NQT - 1 - pi) + 2;   // heavy range; light's is a prefix
  stage(0, 0);
  __syncthreads();
  int buf = 0;

  for (int t = 0; t < nt; ++t) {
    const int kv0 = t * 64;
    if (t + 1 < nt) stage(buf ^ 1, (t + 1) * 64);

    if (kv0 <= q0w + 31) {   // wave-uniform causal skip (light waves idle past their range)
      const unsigned short* kb = &Ks[buf][0];
      const unsigned short* vb = &Vs[buf][0];

      f32x16 st[2];
      __builtin_amdgcn_s_setprio(1);
#pragma unroll
      for (int cc = 0; cc < 2; ++cc) {
        f32x16 z = {};
#pragma unroll
        for (int kkk = 0; kkk < 4; ++kkk) {
          bf16x8 kf = *reinterpret_cast<const bf16x8*>(
              kb + (cc * 32 + l31) * 64 + (((kkk * 2 + hi) ^ sxr) * 8));
          z = __builtin_amdgcn_mfma_f32_32x32x16_bf16(kf, qf[kkk], z, 0, 0, 0);
        }
        st[cc] = z;
      }
      __builtin_amdgcn_s_setprio(0);

      if (kv0 + 63 > q0w) {
        const int kvb = kv0 + 4 * hi;
#pragma unroll
        for (int cc = 0; cc < 2; ++cc)
#pragma unroll
          for (int r = 0; r < 16; ++r) {
            const int kv = kvb + cc * 32 + (r & 3) + 8 * (r >> 2);
            st[cc][r] = (kv <= qq) ? st[cc][r] : -INFINITY;
          }
      }

      float tm = st[0][0];
#pragma unroll
      for (int r = 1; r < 16; ++r) tm = fmaxf(tm, st[0][r]);
#pragma unroll
      for (int r = 0; r < 16; ++r) tm = fmaxf(tm, st[1][r]);
      tm = fmaxf(tm, __shfl_xor(tm, 32));

      if (__any(tm - mrow > 8.0f)) {
        float mn = fmaxf(mrow, tm);
        float al = __builtin_amdgcn_exp2f(mrow - mn);
        mrow = mn;
        lsum *= al;
        ot[0] *= al;
        ot[1] *= al;
      }

#pragma unroll
      for (int cc = 0; cc < 2; ++cc)
#pragma unroll
        for (int r = 0; r < 16; ++r)
          st[cc][r] = __builtin_amdgcn_exp2f(st[cc][r] - mrow);

      unsigned int pk[2][4], pk2[2][4];
#pragma unroll
      for (int cc = 0; cc < 2; ++cc)
#pragma unroll
        for (int g = 0; g < 4; ++g) {
          pk[cc][g]  = cvt_pk_bf16(st[cc][4 * g + 0], st[cc][4 * g + 1]);
          pk2[cc][g] = cvt_pk_bf16(st[cc][4 * g + 2], st[cc][4 * g + 3]);
        }

      __builtin_amdgcn_s_setprio(1);
#pragma unroll
      for (int ks = 0; ks < 4; ++ks) {
        const int cc = ks >> 1, g0 = 2 * (ks & 1), g1 = g0 + 1;
        unsigned int Aw = pk[cc][g0], Bw = pk[cc][g1];
        asm volatile("v_permlane32_swap_b32 %0, %1" : "+v"(Aw), "+v"(Bw));
        unsigned int A2 = pk2[cc][g0], B2 = pk2[cc][g1];
        asm volatile("v_permlane32_swap_b32 %0, %1" : "+v"(A2), "+v"(B2));
        union { unsigned int u[4]; bf16x8 v; } pb;
        pb.u[0] = Aw; pb.u[1] = A2; pb.u[2] = Bw; pb.u[3] = B2;
        lsum = __builtin_amdgcn_mfma_f32_32x32x16_bf16(vones, pb.v, lsum, 0, 0, 0);
#pragma unroll
        for (int dc = 0; dc < 2; ++dc) {
          bf16x8 vf = *reinterpret_cast<const bf16x8*>(
              vb + (dc * 32 + l31) * 64 + (((ks * 2 + hi) ^ sxr) * 8));
          ot[dc] = __builtin_amdgcn_mfma_f32_32x32x16_bf16(vf, pb.v, ot[dc], 0, 0, 0);
        }
      }
      __builtin_amdgcn_s_setprio(0);
    }

    __syncthreads();
    buf ^= 1;
  }

  const float inv = 1.0f / lsum[0];
  __bf16* aout = (__bf16*)attn_out + (size_t)(b * SS + qq) * DD + h * DKK;
#pragma unroll
  for (int dc = 0; dc < 2; ++dc)
#pragma unroll
    for (int g = 0; g < 4; ++g) {
      uint2 pw;
      pw.x = cvt_pk_bf16(ot[dc][4 * g + 0] * inv, ot[dc][4 * g + 1] * inv);
      pw.y = cvt_pk_bf16(ot[dc][4 * g + 2] * inv, ot[dc][4 * g + 3] * inv);
      *reinterpret_cast<uint2*>(aout + dc * 32 + 4 * hi + 8 * g) = pw;
    }
}

// ---------------- launch ----------------
extern "C" void kernel_launch(void* const* d_in, const int* in_sizes, int n_in,
                              void* d_out, int out_size, void* d_ws, size_t ws_size,
                              hipStream_t stream) {
  const float* x = (const float*)d_in[0];
  const float* w_q = (const float*)d_in[1];
  const float* w_k = (const float*)d_in[2];
  const float* w_v = (const float*)d_in[3];
  const float* w_o = (const float*)d_in[4];
  const float* b_o = (const float*)d_in[5];
  float* out = (float*)d_out;

  unsigned short* ws = (unsigned short*)d_ws;
  unsigned short* x_bf = ws;                               // 8192*1024
  unsigned short* w_qkv = x_bf + (size_t)MM * DD;          // 3072*1024
  unsigned short* w_obf = w_qkv + (size_t)NQKV * DD;       // 1024*1024
  unsigned short* qkv = w_obf + (size_t)DD * DD;           // 8192*3072 (V region unused)
  unsigned short* vt = qkv + (size_t)MM * NQKV;            // B*H*DK*S = 8388608
  unsigned short* attn = vt + (size_t)BB * HH * DKK * SS;  // 8192*1024

  // merged converts: [x | w_q | w_k | w_v | w_o] -> contiguous bf16 ws region
  constexpr int TOTAL4 = (MM * DD + 4 * DD * DD) / 4;      // 3145728 float4s
  cvt_all<<<TOTAL4 / 256, 256, 0, stream>>>(x, w_q, w_k, w_v, w_o, (__bf16*)ws);

  // QKV projection (m97-style 128^2, 3 blocks/CU; Q prescaled; V -> vt transposed)
  gemm128<2><<<dim3(NQKV / 128, MM / 128), 256, 0, stream>>>(x_bf, w_qkv, qkv, nullptr, vt, NQKV, DD);

  // attention (fused heavy+light pair, 8 waves/block sharing one KV stream, 2 blocks/CU)
  attn_kernel<<<dim3(NQT / 2, HH, BB), 512, 0, stream>>>(qkv, vt, attn);

  // output projection: [8192,1024] = attn @ w_o^T + b_o
  gemm128<0><<<dim3(DD / 128, MM / 128), 256, 0, stream>>>(attn, w_obf, out, b_o, nullptr, DD, DD);
}